// Round 1
// baseline (89.031 us; speedup 1.0000x reference)
//
#include <hip/hip_runtime.h>

// Depthwise ConvTranspose2d: x(16,64,64,256) f32 -> y(16,128,128,256) f32
// k=4, stride=2, pad=1, NHWC. y[oh,ow,c] = b[c] + sum x[ih,iw,c]*w[oh+1-2ih, ow+1-2iw, c].
// Output 2x2 block {2i-1,2i}x{2j-1,2j} depends on input block {i-1,i}x{j-1,j}.
// One wave = one spatial block across all 256 channels (lane = channel quad, float4).

#define HD 64
#define WD 64
#define OHD 128
#define OWD 128
#define NB 16
#define C4 64            // 256 channels / 4 per float4
#define SPW 65           // spatial blocks per dim (i,j in [0,65))

__device__ __forceinline__ void fma4(float4& a, const float4& x, const float4& w) {
    a.x = fmaf(x.x, w.x, a.x);
    a.y = fmaf(x.y, w.y, a.y);
    a.z = fmaf(x.z, w.z, a.z);
    a.w = fmaf(x.w, w.w, a.w);
}

__global__ __launch_bounds__(256) void dwct_kernel(
    const float* __restrict__ xp, const float* __restrict__ wp,
    const float* __restrict__ bp, float* __restrict__ op,
    int total_s, int nwaves_total)
{
    const int lane = threadIdx.x & 63;
    const int wid  = (int)((blockIdx.x * blockDim.x + threadIdx.x) >> 6);

    const float4* x4 = reinterpret_cast<const float4*>(xp);
    const float4* w4 = reinterpret_cast<const float4*>(wp);
    const float4* b4 = reinterpret_cast<const float4*>(bp);
    float4*       o4 = reinterpret_cast<float4*>(op);

    // Hoist the full 4x4 depthwise kernel for this lane's 4 channels into regs.
    // w layout (kh,kw,1,C): float4 index = (kh*4+kw)*C4 + lane
    float4 wv[16];
#pragma unroll
    for (int t = 0; t < 16; ++t) wv[t] = w4[t * C4 + lane];
    const float4 bv = b4[lane];
    const float4 z  = make_float4(0.f, 0.f, 0.f, 0.f);

    for (int s = wid; s < total_s; s += nwaves_total) {
        int n   = s / (SPW * SPW);
        int rem = s - n * (SPW * SPW);
        int i   = rem / SPW;
        int j   = rem - i * SPW;

        // validity (wave-uniform): input rows ih=i-1 (p0), ih=i (p1); cols likewise.
        const bool p0 = (i > 0), p1 = (i < HD);
        const bool q0 = (j > 0), q1 = (j < WD);

        const int xbase = n * (HD * WD * C4);
        float4 x00 = (p0 && q0) ? x4[xbase + ((i - 1) * WD + (j - 1)) * C4 + lane] : z;
        float4 x01 = (p0 && q1) ? x4[xbase + ((i - 1) * WD + j)       * C4 + lane] : z;
        float4 x10 = (p1 && q0) ? x4[xbase + (i * WD + (j - 1))       * C4 + lane] : z;
        float4 x11 = (p1 && q1) ? x4[xbase + (i * WD + j)             * C4 + lane] : z;

        // out_rs (oh=2i-1+r, ow=2j-1+s2):
        //   += x00 * w[(r+2)*4 + (s2+2)]   (ih=i-1, iw=j-1)
        //   += x01 * w[(r+2)*4 +  s2   ]   (ih=i-1, iw=j)
        //   += x10 * w[ r   *4 + (s2+2)]   (ih=i,   iw=j-1)
        //   += x11 * w[ r   *4 +  s2   ]   (ih=i,   iw=j)
        float4 o00 = bv, o01 = bv, o10 = bv, o11 = bv;

        fma4(o00, x00, wv[2 * 4 + 2]); fma4(o00, x01, wv[2 * 4 + 0]);
        fma4(o00, x10, wv[0 * 4 + 2]); fma4(o00, x11, wv[0 * 4 + 0]);

        fma4(o01, x00, wv[2 * 4 + 3]); fma4(o01, x01, wv[2 * 4 + 1]);
        fma4(o01, x10, wv[0 * 4 + 3]); fma4(o01, x11, wv[0 * 4 + 1]);

        fma4(o10, x00, wv[3 * 4 + 2]); fma4(o10, x01, wv[3 * 4 + 0]);
        fma4(o10, x10, wv[1 * 4 + 2]); fma4(o10, x11, wv[1 * 4 + 0]);

        fma4(o11, x00, wv[3 * 4 + 3]); fma4(o11, x01, wv[3 * 4 + 1]);
        fma4(o11, x10, wv[1 * 4 + 3]); fma4(o11, x11, wv[1 * 4 + 1]);

        const int oh0 = 2 * i - 1;          // row for r=0 (valid iff p0)
        const int ow0 = 2 * j - 1;          // col for s2=0 (valid iff q0)
        const int obase = n * (OHD * OWD * C4);

        if (p0) {
            const int rb = obase + oh0 * (OWD * C4);
            if (q0) o4[rb + ow0 * C4 + lane]       = o00;
            if (q1) o4[rb + (ow0 + 1) * C4 + lane] = o01;
        }
        if (p1) {
            const int rb = obase + (oh0 + 1) * (OWD * C4);
            if (q0) o4[rb + ow0 * C4 + lane]       = o10;
            if (q1) o4[rb + (ow0 + 1) * C4 + lane] = o11;
        }
    }
}

extern "C" void kernel_launch(void* const* d_in, const int* in_sizes, int n_in,
                              void* d_out, int out_size, void* d_ws, size_t ws_size,
                              hipStream_t stream) {
    const float* x = (const float*)d_in[0];
    const float* w = (const float*)d_in[1];
    const float* b = (const float*)d_in[2];
    float* out = (float*)d_out;

    const int total_s = NB * SPW * SPW;   // 16*65*65 = 67600 wave-iterations
    const int threads = 256;
    const int blocks  = 2048;             // grid-stride; 8192 waves
    const int nwaves  = blocks * (threads / 64);

    hipLaunchKernelGGL(dwct_kernel, dim3(blocks), dim3(threads), 0, stream,
                       x, w, b, out, total_s, nwaves);
}